// Round 5
// baseline (1908.754 us; speedup 1.0000x reference)
//
#include <hip/hip_runtime.h>

#define SEQ   512
#define NTHR  512
#define NBLK  256
#define KT    8      // LN combine every KT steps

typedef _Float16 f16x8 __attribute__((ext_vector_type(8)));
typedef float    f32x4 __attribute__((ext_vector_type(4)));

#define MFMA(a, b, c) __builtin_amdgcn_mfma_f32_16x16x32_f16((a), (b), (c), 0, 0, 0)

// sign-safe tanh via 2*sigmoid(2x)-1 (saturates to +/-1, no Inf/NaN for finite x)
__device__ __forceinline__ float tanh_(float x) {
    return fmaf(2.0f, __builtin_amdgcn_rcpf(1.0f + __builtin_amdgcn_exp2f(x * -2.8853900817779268f)), -1.0f);
}

#define SWZ(v, IMM) __int_as_float(__builtin_amdgcn_ds_swizzle(__float_as_int(v), IMM))

// Distributed gate post-processing. Lane quad {bc, bc+4, bc+8, bc+12} shares one
// (m, b) gate-set; lane k=bc>>2 evaluates gate k with the unified formula
// y = ga*rcp(1+exp2(gb*x)) + gc, then xor-4/8/12 swizzles gather i,f,g,o.
// Real c/h state lives on k==0 lanes (bc<4); other lanes compute bounded garbage.
#define GATEPOST(ACC, CREF, HN)                                                \
    {                                                                          \
        float xs = k1b ? ACC[1] : ACC[0];                                      \
        float xu = k1b ? ACC[3] : ACC[2];                                      \
        xs = k2b ? xu : xs;                                                    \
        const float y  = fmaf(ga, __builtin_amdgcn_rcpf(1.0f + __builtin_amdgcn_exp2f(gb * xs)), gc); \
        const float yf = SWZ(y, 0x101F);   /* xor 4  */                        \
        const float yg = SWZ(y, 0x201F);   /* xor 8  */                        \
        const float yo = SWZ(y, 0x301F);   /* xor 12 */                        \
        CREF = fmaf(yf, CREF, y * yg);                                         \
        HN   = yo * tanh_(CREF);                                               \
    }

#define DO_LAYER(L, WF)                                                        \
    {                                                                          \
        const char* bIn   = bNew + ((L) - 1) * 512;                            \
        const char* bSelf = bOld + (L) * 512;                                  \
        const f16x8 hI0 = *(const f16x8*)(bIn + a0);                           \
        const f16x8 hI1 = *(const f16x8*)(bIn + a1);                           \
        const f16x8 hS0 = *(const f16x8*)(bSelf + a0);                         \
        const f16x8 hS1 = *(const f16x8*)(bSelf + a1);                         \
        f32x4 acc0 = *(const f32x4*)(bldsB + (L) * 1024);                      \
        f32x4 acc1 = *(const f32x4*)(bldsB + (L) * 1024 + 64);                 \
        acc0 = MFMA(WF[0][0], hI0, acc0);  acc1 = MFMA(WF[1][0], hI0, acc1);   \
        acc0 = MFMA(WF[0][1], hI1, acc0);  acc1 = MFMA(WF[1][1], hI1, acc1);   \
        acc0 = MFMA(WF[0][2], hS0, acc0);  acc1 = MFMA(WF[1][2], hS0, acc1);   \
        acc0 = MFMA(WF[0][3], hS1, acc0);  acc1 = MFMA(WF[1][3], hS1, acc1);   \
        float cv0 = cst[L][0], cv1 = cst[L][1];                                \
        GATEPOST(acc0, cv0, hn0)                                               \
        GATEPOST(acc1, cv1, hn1)                                               \
        cst[L][0] = cv0; cst[L][1] = cv1;                                      \
        char* hw = bNew + (L) * 512;                                           \
        if (gl) { *(_Float16*)(hw + wr0) = (_Float16)hn0;                      \
                  *(_Float16*)(hw + wr1) = (_Float16)hn1; }                    \
    }

__global__ __launch_bounds__(NTHR, 4) void lstm4_mfma2(
    const float* __restrict__ x,
    const float* __restrict__ W0, const float* __restrict__ B0,
    const float* __restrict__ W1, const float* __restrict__ B1,
    const float* __restrict__ W2, const float* __restrict__ B2,
    const float* __restrict__ W3, const float* __restrict__ B3,
    const float* __restrict__ ln_g, const float* __restrict__ ln_b,
    const float* __restrict__ Wout, const float* __restrict__ bout,
    float* __restrict__ out)
{
    __shared__ __align__(16) _Float16 hbuf[2][4][4][64];   // 4 KB
    __shared__ float xall[4][SEQ];                         // 8 KB
    __shared__ float part[KT][8][4][4][3];                 // 12 KB raw LN partials
    __shared__ __align__(16) float blds[4 * 256];          // 4 KB biases
    __shared__ float sconst[2];

    const int tid  = threadIdx.x;
    const int lane = tid & 63;
    const int w    = tid >> 6;
    const int lam  = lane >> 4;
    const int bc   = lane & 15;
    const int br   = bc & 3;
    const int bb   = blockIdx.x;
    const int T0   = 2 * w, T1 = 2 * w + 1;

    // ---- stage x, zero h ----
    for (int i = tid; i < 4 * SEQ; i += NTHR)
        xall[i >> 9][i & 511] = x[bb * 4 * SEQ + i];
    for (int i = tid; i < 2 * 4 * 4 * 64; i += NTHR)
        ((_Float16*)hbuf)[i] = (_Float16)0.0f;

    // ---- biases -> LDS: blds[L*256 + (w*2+T)*16 + lam*4 + r] = B_L[r*64+(2w+T)*4+lam]
    for (int i = tid; i < 1024; i += NTHR) {
        const int L = i >> 8, idx = i & 255;
        const int r = idx & 3, lm = (idx >> 2) & 3, tt = (idx >> 4) & 1, w8 = idx >> 5;
        const int col = r * 64 + (2 * w8 + tt) * 4 + lm;
        const float* Bp = (L == 0) ? B0 : (L == 1) ? B1 : (L == 2) ? B2 : B3;
        blds[i] = Bp[col];
    }

    if (tid < 64) {
        float a = ln_g[tid] * Wout[tid];
        float b = ln_b[tid] * Wout[tid];
#pragma unroll
        for (int off = 32; off > 0; off >>= 1) {
            a += __shfl_xor(a, off, 64);
            b += __shfl_xor(b, off, 64);
        }
        if (tid == 0) { sconst[0] = a; sconst[1] = b; }
    }

    // ---- A-fragments: W^T, gate-permuted (row rho -> gate=rho&3, m=T*4+rho>>2) ----
    const int rho   = bc;
    const int colA0 = (rho & 3) * 64 + T0 * 4 + (rho >> 2);
    const int colA1 = (rho & 3) * 64 + T1 * 4 + (rho >> 2);

    f16x8 wf0[2][2], wf1[2][4], wf2[2][4], wf3[2][4];
#pragma unroll
    for (int kt = 0; kt < 2; ++kt) {
        const int kb = 1 + kt * 32 + lam * 8;
#pragma unroll
        for (int e = 0; e < 8; ++e) {
            wf0[0][kt][e] = (_Float16)W0[(kb + e) * 256 + colA0];
            wf0[1][kt][e] = (_Float16)W0[(kb + e) * 256 + colA1];
        }
    }
#pragma unroll
    for (int kt = 0; kt < 4; ++kt) {
        const int kb = kt * 32 + lam * 8;
#pragma unroll
        for (int e = 0; e < 8; ++e) {
            wf1[0][kt][e] = (_Float16)W1[(kb + e) * 256 + colA0];
            wf1[1][kt][e] = (_Float16)W1[(kb + e) * 256 + colA1];
            wf2[0][kt][e] = (_Float16)W2[(kb + e) * 256 + colA0];
            wf2[1][kt][e] = (_Float16)W2[(kb + e) * 256 + colA1];
            wf3[0][kt][e] = (_Float16)W3[(kb + e) * 256 + colA0];
            wf3[1][kt][e] = (_Float16)W3[(kb + e) * 256 + colA1];
        }
    }

    // x-weights (W0 row 0), per C-lane view
    float wx[2][4];
#pragma unroll
    for (int r = 0; r < 4; ++r) {
        wx[0][r] = W0[r * 64 + T0 * 4 + lam];
        wx[1][r] = W0[r * 64 + T1 * 4 + lam];
    }
    const int   m0  = T0 * 4 + lam, m1 = T1 * 4 + lam;
    const float gw0 = ln_g[m0] * Wout[m0];
    const float gw1 = ln_g[m1] * Wout[m1];
    const float bo  = bout[0];

    // LDS offsets (round-4 layout, 16B-chunk XOR swizzle)
    const int a0  = br * 128 + ((lam)     ^ br) * 16;
    const int a1  = br * 128 + ((4 + lam) ^ br) * 16;
    const int wr0 = bc * 128 + (((m0 >> 3) ^ bc) * 16) + (m0 & 7) * 2;
    const int wr1 = bc * 128 + (((m1 >> 3) ^ bc) * 16) + (m1 & 7) * 2;
    const bool gl = (bc < 4);

    // distributed-gate per-lane constants
    const bool k1b = (bc & 4) != 0;
    const bool k2b = (bc & 8) != 0;
    const bool isg = ((bc >> 2) == 2);
    const float ga = isg ? 2.0f : 1.0f;
    const float gb = isg ? -2.8853900817779268f : -1.4426950408889634f;
    const float gc = isg ? -1.0f : 0.0f;

    float cst[4][2] = {{0.f,0.f},{0.f,0.f},{0.f,0.f},{0.f,0.f}};
    char* const hb    = (char*)hbuf;
    const char* bldsB = (const char*)blds + w * 128 + lam * 16;

    __syncthreads();
    const float Sgw = sconst[0];
    const float Sbw = sconst[1] + bo;

    int p = 0;
    for (int t = 0; t < SEQ; ++t) {
        char* bOld = hb + p * 2048;
        char* bNew = hb + (p ^ 1) * 2048;
        float hn0 = 0.0f, hn1 = 0.0f;

        // ---------------- layer 0 ----------------
        {
            const f16x8 hS0 = *(const f16x8*)(bOld + a0);
            const f16x8 hS1 = *(const f16x8*)(bOld + a1);
            const float xv  = xall[br][t];
            f32x4 acc0 = *(const f32x4*)(bldsB);
            f32x4 acc1 = *(const f32x4*)(bldsB + 64);
#pragma unroll
            for (int r = 0; r < 4; ++r) {
                acc0[r] = fmaf(xv, wx[0][r], acc0[r]);
                acc1[r] = fmaf(xv, wx[1][r], acc1[r]);
            }
            acc0 = MFMA(wf0[0][0], hS0, acc0);  acc1 = MFMA(wf0[1][0], hS0, acc1);
            acc0 = MFMA(wf0[0][1], hS1, acc0);  acc1 = MFMA(wf0[1][1], hS1, acc1);
            float cv0 = cst[0][0], cv1 = cst[0][1];
            GATEPOST(acc0, cv0, hn0)
            GATEPOST(acc1, cv1, hn1)
            cst[0][0] = cv0; cst[0][1] = cv1;
            char* hw = bNew;
            if (gl) { *(_Float16*)(hw + wr0) = (_Float16)hn0;
                      *(_Float16*)(hw + wr1) = (_Float16)hn1; }
        }
        __syncthreads();
        DO_LAYER(1, wf1)
        __syncthreads();
        DO_LAYER(2, wf2)
        __syncthreads();
        DO_LAYER(3, wf3)

        // raw LN partials (no shuffles, no extra barrier)
        if (gl) {
            float* pp = &part[t & (KT - 1)][w][lam][bc][0];
            pp[0] = hn0 + hn1;
            pp[1] = fmaf(hn0, hn0, hn1 * hn1);
            pp[2] = fmaf(hn0, gw0, hn1 * gw1);
        }

        // ---------------- bulk LN + projection every KT steps ----------------
        if ((t & (KT - 1)) == (KT - 1)) {
            __syncthreads();
            const int row = tid >> 4, sub = tid & 15;   // 32 rows x 16 lanes
            const int tt = row >> 2, b = row & 3;
            const int p0i = sub * 2, p1i = p0i + 1;
            float s1 = part[tt][p0i >> 2][p0i & 3][b][0] + part[tt][p1i >> 2][p1i & 3][b][0];
            float s2 = part[tt][p0i >> 2][p0i & 3][b][1] + part[tt][p1i >> 2][p1i & 3][b][1];
            float s3 = part[tt][p0i >> 2][p0i & 3][b][2] + part[tt][p1i >> 2][p1i & 3][b][2];
#pragma unroll
            for (int off = 1; off <= 8; off <<= 1) {
                s1 += __shfl_xor(s1, off, 64);
                s2 += __shfl_xor(s2, off, 64);
                s3 += __shfl_xor(s3, off, 64);
            }
            if (sub == 0) {
                const float mu = s1 * (1.0f / 64.0f);
                float var = fmaf(s2, 1.0f / 64.0f, -mu * mu);
                var = fmaxf(var, 0.0f);
                const float rs = rsqrtf(var + 1e-5f);
                out[(bb * 4 + b) * SEQ + (t - (KT - 1)) + tt] = fmaf(rs, fmaf(-mu, Sgw, s3), Sbw);
            }
        }
        p ^= 1;
    }
}

extern "C" void kernel_launch(void* const* d_in, const int* in_sizes, int n_in,
                              void* d_out, int out_size, void* d_ws, size_t ws_size,
                              hipStream_t stream)
{
    const float* x    = (const float*)d_in[0];
    const float* W0   = (const float*)d_in[1];
    const float* B0   = (const float*)d_in[2];
    const float* W1   = (const float*)d_in[3];
    const float* B1   = (const float*)d_in[4];
    const float* W2   = (const float*)d_in[5];
    const float* B2   = (const float*)d_in[6];
    const float* W3   = (const float*)d_in[7];
    const float* B3   = (const float*)d_in[8];
    const float* ln_g = (const float*)d_in[9];
    const float* ln_b = (const float*)d_in[10];
    const float* Wout = (const float*)d_in[11];
    const float* bout = (const float*)d_in[12];
    float* out = (float*)d_out;

    lstm4_mfma2<<<NBLK, NTHR, 0, stream>>>(x, W0, B0, W1, B1, W2, B2, W3, B3,
                                           ln_g, ln_b, Wout, bout, out);
}

// Round 6
// 795.396 us; speedup vs baseline: 2.3998x; 2.3998x over previous
//
#include <hip/hip_runtime.h>

#define SEQ   512
#define NTHR  512
#define NBLK  256
#define KT    8      // LN combine every KT steps

typedef _Float16 f16x8 __attribute__((ext_vector_type(8)));
typedef float    f32x4 __attribute__((ext_vector_type(4)));

#define MFMA(a, b, c) __builtin_amdgcn_mfma_f32_16x16x32_f16((a), (b), (c), 0, 0, 0)

// sign-safe tanh via 2*sigmoid(2x)-1 (saturates to +/-1, no Inf/NaN for finite x)
__device__ __forceinline__ float tanh_(float x) {
    return fmaf(2.0f, __builtin_amdgcn_rcpf(1.0f + __builtin_amdgcn_exp2f(x * -2.8853900817779268f)), -1.0f);
}

#define SWZ(v, IMM) __int_as_float(__builtin_amdgcn_ds_swizzle(__float_as_int(v), IMM))

// Distributed gate post-processing. Lane quad {bc, bc+4, bc+8, bc+12} shares one
// (m, b) gate-set; lane k=bc>>2 evaluates gate k with the unified formula
// y = ga*rcp(1+exp2(gb*x)) + gc, then xor-4/8/12 swizzles gather i,f,g,o.
// Real c/h state lives on k==0 lanes (bc<4); other lanes compute bounded garbage.
#define GATEPOST(ACC, CREF, HN)                                                \
    {                                                                          \
        float xs = k1b ? ACC[1] : ACC[0];                                      \
        float xu = k1b ? ACC[3] : ACC[2];                                      \
        xs = k2b ? xu : xs;                                                    \
        const float y  = fmaf(ga, __builtin_amdgcn_rcpf(1.0f + __builtin_amdgcn_exp2f(gb * xs)), gc); \
        const float yf = SWZ(y, 0x101F);   /* xor 4  */                        \
        const float yg = SWZ(y, 0x201F);   /* xor 8  */                        \
        const float yo = SWZ(y, 0x301F);   /* xor 12 */                        \
        CREF = fmaf(yf, CREF, y * yg);                                         \
        HN   = yo * tanh_(CREF);                                               \
    }

// layer body with pre-loaded operand fragments
#define LAYER_BODY(L, WF, HI0, HI1, HS0, HS1)                                  \
    {                                                                          \
        f32x4 acc0 = *(const f32x4*)(bldsB + (L) * 1024);                      \
        f32x4 acc1 = *(const f32x4*)(bldsB + (L) * 1024 + 64);                 \
        acc0 = MFMA(WF[0][0], HI0, acc0);  acc1 = MFMA(WF[1][0], HI0, acc1);   \
        acc0 = MFMA(WF[0][1], HI1, acc0);  acc1 = MFMA(WF[1][1], HI1, acc1);   \
        acc0 = MFMA(WF[0][2], HS0, acc0);  acc1 = MFMA(WF[1][2], HS0, acc1);   \
        acc0 = MFMA(WF[0][3], HS1, acc0);  acc1 = MFMA(WF[1][3], HS1, acc1);   \
        float cv0 = cst[L][0], cv1 = cst[L][1];                                \
        GATEPOST(acc0, cv0, hn0)                                               \
        GATEPOST(acc1, cv1, hn1)                                               \
        cst[L][0] = cv0; cst[L][1] = cv1;                                      \
        char* hw = bNew + (L) * 512;                                           \
        if (gl) { *(_Float16*)(hw + wr0) = (_Float16)hn0;                      \
                  *(_Float16*)(hw + wr1) = (_Float16)hn1; }                    \
    }

__global__ __launch_bounds__(NTHR, 1) void lstm4_mfma3(
    const float* __restrict__ x,
    const float* __restrict__ W0, const float* __restrict__ B0,
    const float* __restrict__ W1, const float* __restrict__ B1,
    const float* __restrict__ W2, const float* __restrict__ B2,
    const float* __restrict__ W3, const float* __restrict__ B3,
    const float* __restrict__ ln_g, const float* __restrict__ ln_b,
    const float* __restrict__ Wout, const float* __restrict__ bout,
    float* __restrict__ out)
{
    __shared__ __align__(16) _Float16 hbuf[2][4][4][64];   // 4 KB
    __shared__ float xall[4][SEQ];                         // 8 KB
    __shared__ float part[KT][8][4][4][3];                 // 12 KB raw LN partials
    __shared__ __align__(16) float blds[4 * 256];          // 4 KB biases
    __shared__ float sconst[2];

    const int tid  = threadIdx.x;
    const int lane = tid & 63;
    const int w    = tid >> 6;
    const int lam  = lane >> 4;
    const int bc   = lane & 15;
    const int br   = bc & 3;
    const int bb   = blockIdx.x;
    const int T0   = 2 * w, T1 = 2 * w + 1;

    // ---- stage x, zero h ----
    for (int i = tid; i < 4 * SEQ; i += NTHR)
        xall[i >> 9][i & 511] = x[bb * 4 * SEQ + i];
    for (int i = tid; i < 2 * 4 * 4 * 64; i += NTHR)
        ((_Float16*)hbuf)[i] = (_Float16)0.0f;

    // ---- biases -> LDS: blds[L*256 + (w*2+T)*16 + lam*4 + r] = B_L[r*64+(2w+T)*4+lam]
    for (int i = tid; i < 1024; i += NTHR) {
        const int L = i >> 8, idx = i & 255;
        const int r = idx & 3, lm = (idx >> 2) & 3, tt = (idx >> 4) & 1, w8 = idx >> 5;
        const int col = r * 64 + (2 * w8 + tt) * 4 + lm;
        const float* Bp = (L == 0) ? B0 : (L == 1) ? B1 : (L == 2) ? B2 : B3;
        blds[i] = Bp[col];
    }

    if (tid < 64) {
        float a = ln_g[tid] * Wout[tid];
        float b = ln_b[tid] * Wout[tid];
#pragma unroll
        for (int off = 32; off > 0; off >>= 1) {
            a += __shfl_xor(a, off, 64);
            b += __shfl_xor(b, off, 64);
        }
        if (tid == 0) { sconst[0] = a; sconst[1] = b; }
    }

    // ---- A-fragments: W^T, gate-permuted (row rho -> gate=rho&3, m=T*4+rho>>2) ----
    const int rho   = bc;
    const int colA0 = (rho & 3) * 64 + T0 * 4 + (rho >> 2);
    const int colA1 = (rho & 3) * 64 + T1 * 4 + (rho >> 2);

    f16x8 wf0[2][2], wf1[2][4], wf2[2][4], wf3[2][4];
#pragma unroll
    for (int kt = 0; kt < 2; ++kt) {
        const int kb = 1 + kt * 32 + lam * 8;
#pragma unroll
        for (int e = 0; e < 8; ++e) {
            wf0[0][kt][e] = (_Float16)W0[(kb + e) * 256 + colA0];
            wf0[1][kt][e] = (_Float16)W0[(kb + e) * 256 + colA1];
        }
    }
#pragma unroll
    for (int kt = 0; kt < 4; ++kt) {
        const int kb = kt * 32 + lam * 8;
#pragma unroll
        for (int e = 0; e < 8; ++e) {
            wf1[0][kt][e] = (_Float16)W1[(kb + e) * 256 + colA0];
            wf1[1][kt][e] = (_Float16)W1[(kb + e) * 256 + colA1];
            wf2[0][kt][e] = (_Float16)W2[(kb + e) * 256 + colA0];
            wf2[1][kt][e] = (_Float16)W2[(kb + e) * 256 + colA1];
            wf3[0][kt][e] = (_Float16)W3[(kb + e) * 256 + colA0];
            wf3[1][kt][e] = (_Float16)W3[(kb + e) * 256 + colA1];
        }
    }

    // x-weights (W0 row 0), per C-lane view
    float wx[2][4];
#pragma unroll
    for (int r = 0; r < 4; ++r) {
        wx[0][r] = W0[r * 64 + T0 * 4 + lam];
        wx[1][r] = W0[r * 64 + T1 * 4 + lam];
    }
    const int   m0  = T0 * 4 + lam, m1 = T1 * 4 + lam;
    const float gw0 = ln_g[m0] * Wout[m0];
    const float gw1 = ln_g[m1] * Wout[m1];
    const float bo  = bout[0];

    // LDS offsets (16B-chunk XOR swizzle)
    const int a0  = br * 128 + ((lam)     ^ br) * 16;
    const int a1  = br * 128 + ((4 + lam) ^ br) * 16;
    const int wr0 = bc * 128 + (((m0 >> 3) ^ bc) * 16) + (m0 & 7) * 2;
    const int wr1 = bc * 128 + (((m1 >> 3) ^ bc) * 16) + (m1 & 7) * 2;
    const bool gl = (bc < 4);

    // distributed-gate per-lane constants
    const bool k1b = (bc & 4) != 0;
    const bool k2b = (bc & 8) != 0;
    const bool isg = ((bc >> 2) == 2);
    const float ga = isg ? 2.0f : 1.0f;
    const float gb = isg ? -2.8853900817779268f : -1.4426950408889634f;
    const float gc = isg ? -1.0f : 0.0f;

    float cst[4][2] = {{0.f,0.f},{0.f,0.f},{0.f,0.f},{0.f,0.f}};
    char* const hb    = (char*)hbuf;
    const char* bldsB = (const char*)blds + w * 128 + lam * 16;

    __syncthreads();
    const float Sgw = sconst[0];
    const float Sbw = sconst[1] + bo;

    int p = 0;
    for (int t = 0; t < SEQ; ++t) {
        char* bOld = hb + p * 2048;
        char* bNew = hb + (p ^ 1) * 2048;
        float hn0 = 0.0f, hn1 = 0.0f;

        // ---------------- layer 0 ----------------
        {
            const f16x8 hS0 = *(const f16x8*)(bOld + a0);
            const f16x8 hS1 = *(const f16x8*)(bOld + a1);
            const float xv  = xall[br][t];
            f32x4 acc0 = *(const f32x4*)(bldsB);
            f32x4 acc1 = *(const f32x4*)(bldsB + 64);
#pragma unroll
            for (int r = 0; r < 4; ++r) {
                acc0[r] = fmaf(xv, wx[0][r], acc0[r]);
                acc1[r] = fmaf(xv, wx[1][r], acc1[r]);
            }
            acc0 = MFMA(wf0[0][0], hS0, acc0);  acc1 = MFMA(wf0[1][0], hS0, acc1);
            acc0 = MFMA(wf0[0][1], hS1, acc0);  acc1 = MFMA(wf0[1][1], hS1, acc1);
            float cv0 = cst[0][0], cv1 = cst[0][1];
            GATEPOST(acc0, cv0, hn0)
            GATEPOST(acc1, cv1, hn1)
            cst[0][0] = cv0; cst[0][1] = cv1;
            char* hw = bNew;
            if (gl) { *(_Float16*)(hw + wr0) = (_Float16)hn0;
                      *(_Float16*)(hw + wr1) = (_Float16)hn1; }
        }
        __syncthreads();

        // ---- prefetch all stable operands for layers 1..3 (written >=1 barrier ago):
        //      layer1 in-h (just barriered), layer1/2/3 self-h (old parity, stable)
        const f16x8 hI1_0 = *(const f16x8*)(bNew + a0);
        const f16x8 hI1_1 = *(const f16x8*)(bNew + a1);
        const f16x8 hS1_0 = *(const f16x8*)(bOld + 512 + a0);
        const f16x8 hS1_1 = *(const f16x8*)(bOld + 512 + a1);
        const f16x8 hS2_0 = *(const f16x8*)(bOld + 1024 + a0);
        const f16x8 hS2_1 = *(const f16x8*)(bOld + 1024 + a1);
        const f16x8 hS3_0 = *(const f16x8*)(bOld + 1536 + a0);
        const f16x8 hS3_1 = *(const f16x8*)(bOld + 1536 + a1);

        LAYER_BODY(1, wf1, hI1_0, hI1_1, hS1_0, hS1_1)
        __syncthreads();
        {
            const f16x8 hI2_0 = *(const f16x8*)(bNew + 512 + a0);
            const f16x8 hI2_1 = *(const f16x8*)(bNew + 512 + a1);
            LAYER_BODY(2, wf2, hI2_0, hI2_1, hS2_0, hS2_1)
        }
        __syncthreads();
        {
            const f16x8 hI3_0 = *(const f16x8*)(bNew + 1024 + a0);
            const f16x8 hI3_1 = *(const f16x8*)(bNew + 1024 + a1);
            LAYER_BODY(3, wf3, hI3_0, hI3_1, hS3_0, hS3_1)
        }

        // raw LN partials (no shuffles, no extra barrier)
        if (gl) {
            float* pp = &part[t & (KT - 1)][w][lam][bc][0];
            pp[0] = hn0 + hn1;
            pp[1] = fmaf(hn0, hn0, hn1 * hn1);
            pp[2] = fmaf(hn0, gw0, hn1 * gw1);
        }

        // ---------------- bulk LN + projection every KT steps ----------------
        if ((t & (KT - 1)) == (KT - 1)) {
            __syncthreads();
            const int row = tid >> 4, sub = tid & 15;   // 32 rows x 16 lanes
            const int tt = row >> 2, b = row & 3;
            const int p0i = sub * 2, p1i = p0i + 1;
            float s1 = part[tt][p0i >> 2][p0i & 3][b][0] + part[tt][p1i >> 2][p1i & 3][b][0];
            float s2 = part[tt][p0i >> 2][p0i & 3][b][1] + part[tt][p1i >> 2][p1i & 3][b][1];
            float s3 = part[tt][p0i >> 2][p0i & 3][b][2] + part[tt][p1i >> 2][p1i & 3][b][2];
#pragma unroll
            for (int off = 1; off <= 8; off <<= 1) {
                s1 += __shfl_xor(s1, off, 64);
                s2 += __shfl_xor(s2, off, 64);
                s3 += __shfl_xor(s3, off, 64);
            }
            if (sub == 0) {
                const float mu = s1 * (1.0f / 64.0f);
                float var = fmaf(s2, 1.0f / 64.0f, -mu * mu);
                var = fmaxf(var, 0.0f);
                const float rs = rsqrtf(var + 1e-5f);
                out[(bb * 4 + b) * SEQ + (t - (KT - 1)) + tt] = fmaf(rs, fmaf(-mu, Sgw, s3), Sbw);
            }
        }
        p ^= 1;
    }
}

extern "C" void kernel_launch(void* const* d_in, const int* in_sizes, int n_in,
                              void* d_out, int out_size, void* d_ws, size_t ws_size,
                              hipStream_t stream)
{
    const float* x    = (const float*)d_in[0];
    const float* W0   = (const float*)d_in[1];
    const float* B0   = (const float*)d_in[2];
    const float* W1   = (const float*)d_in[3];
    const float* B1   = (const float*)d_in[4];
    const float* W2   = (const float*)d_in[5];
    const float* B2   = (const float*)d_in[6];
    const float* W3   = (const float*)d_in[7];
    const float* B3   = (const float*)d_in[8];
    const float* ln_g = (const float*)d_in[9];
    const float* ln_b = (const float*)d_in[10];
    const float* Wout = (const float*)d_in[11];
    const float* bout = (const float*)d_in[12];
    float* out = (float*)d_out;

    lstm4_mfma3<<<NBLK, NTHR, 0, stream>>>(x, W0, B0, W1, B1, W2, B2, W3, B3,
                                           ln_g, ln_b, Wout, bout, out);
}